// Round 2
// baseline (974.097 us; speedup 1.0000x reference)
//
#include <hip/hip_runtime.h>
#include <hip/hip_bf16.h>

// ---------- bf16 bit helpers (weights-in-LDS packing only) ----------
static __device__ __forceinline__ float bflo2f(unsigned int w) {
    union { unsigned int u; float f; } c; c.u = w << 16; return c.f;
}
static __device__ __forceinline__ float bfhi2f(unsigned int w) {
    union { unsigned int u; float f; } c; c.u = w & 0xffff0000u; return c.f;
}
static __device__ __forceinline__ unsigned int f2bf(float f) {
    union { float f; unsigned int u; } c; c.f = f;
    unsigned int u = c.u;
    u = u + 0x7fffu + ((u >> 16) & 1u);   // round-to-nearest-even
    return u >> 16;
}

// ---------- kernel 1: scatter-add x[src] into agg[dst], count deg ----------
// one wave (64 lanes) per edge; lane l handles features 2l, 2l+1 (float2, 512B/wave)
__global__ __launch_bounds__(256) void k_scatter(
        const float* __restrict__ x,
        const int* __restrict__ src, const int* __restrict__ dst,
        float* __restrict__ agg, float* __restrict__ deg, int E)
{
    int e    = (int)((blockIdx.x * 256u + threadIdx.x) >> 6);
    int lane = threadIdx.x & 63;
    if (e >= E) return;
    int s = src[e];
    int d = dst[e];
    float2 v = ((const float2*)(x + (size_t)s * 128u))[lane];
    float* ar = agg + (size_t)d * 128u;
    unsafeAtomicAdd(ar + 2 * lane,     v.x);     // global_atomic_add_f32
    unsafeAtomicAdd(ar + 2 * lane + 1, v.y);
    if (lane == 0) unsafeAtomicAdd(deg + d, 1.0f);
}

// ---------- kernel 2: out[i] = x[i]@Wr^T + (agg[i]/max(deg,1))@Wl^T + bl ----
// Weights staged k-major in LDS as packed bf16 pairs:
//   WT2[k][l] = { W[l][k], W[l+64][k] }  for k<128: Wr, k>=128: Wl   (64 KiB)
// LDS read WT2[k][lane]: bank = lane%32 -> 2 lanes/bank (free, broadcast-free).
// One wave per out row; lane computes h=lane and h=lane+64.
// NOTE: agg may alias out (ws fallback) -> no __restrict__ on agg/out; each
// out row is read (agg) fully before being written, by its single owning wave.
__global__ __launch_bounds__(256) void k_combine(
        const float* __restrict__ x,
        const float* agg, const float* __restrict__ deg,
        const float* __restrict__ Wr, const float* __restrict__ Wl,
        const float* __restrict__ bl,
        float* out, int N)
{
    __shared__ unsigned int WT2[256][64];            // 65536 B
    for (int idx = threadIdx.x; idx < 256 * 64; idx += 256) {
        int k = idx >> 6, l = idx & 63;
        const float* Wsrc = (k < 128) ? Wr : Wl;
        int kk = k & 127;
        unsigned int lo = f2bf(Wsrc[(size_t)l * 128 + kk]);
        unsigned int hi = f2bf(Wsrc[(size_t)(l + 64) * 128 + kk]);
        WT2[k][l] = lo | (hi << 16);
    }
    __syncthreads();

    int wid = threadIdx.x >> 6, lane = threadIdx.x & 63;
    float b0 = bl[lane];
    float b1 = bl[lane + 64];

    for (int row = blockIdx.x * 4 + wid; row < N; row += gridDim.x * 4) {
        const float4* xr = (const float4*)(x   + (size_t)row * 128);
        const float4* ar = (const float4*)(agg + (size_t)row * 128);
        float inv = 1.0f / fmaxf(deg[row], 1.0f);
        float acc0 = b0, acc1 = b1;

        #pragma unroll
        for (int c = 0; c < 32; ++c) {               // K half 1: x with Wr
            float4 q = xr[c];                         // broadcast load (uniform addr)
            #pragma unroll
            for (int j = 0; j < 4; ++j) {
                int k = c * 4 + j;
                float r = (&q.x)[j];
                unsigned int w = WT2[k][lane];
                acc0 = fmaf(r, bflo2f(w), acc0);
                acc1 = fmaf(r, bfhi2f(w), acc1);
            }
        }
        #pragma unroll
        for (int c = 0; c < 32; ++c) {               // K half 2: mean(agg) with Wl
            float4 q = ar[c];
            #pragma unroll
            for (int j = 0; j < 4; ++j) {
                int k = 128 + c * 4 + j;
                float r = (&q.x)[j] * inv;
                unsigned int w = WT2[k][lane];
                acc0 = fmaf(r, bflo2f(w), acc0);
                acc1 = fmaf(r, bfhi2f(w), acc1);
            }
        }
        out[(size_t)row * 128 + lane]      = acc0;
        out[(size_t)row * 128 + lane + 64] = acc1;
    }
}

extern "C" void kernel_launch(void* const* d_in, const int* in_sizes, int n_in,
                              void* d_out, int out_size, void* d_ws, size_t ws_size,
                              hipStream_t stream)
{
    const float* x  = (const float*)d_in[0];
    const int*   ei = (const int*)d_in[1];
    const float* Wl = (const float*)d_in[2];
    const float* bl = (const float*)d_in[3];
    const float* Wr = (const float*)d_in[4];
    float*      out = (float*)d_out;

    int N = in_sizes[0] / 128;
    int E = in_sizes[1] / 2;
    const int* src = ei;          // edge_index[0] = source nodes (j)
    const int* dst = ei + E;      // edge_index[1] = destination nodes (i)

    size_t aggB = (size_t)N * 128 * 4;
    size_t degB = (size_t)N * 4;

    float *agg, *deg;
    if (ws_size >= aggB + degB) {
        agg = (float*)d_ws;
        deg = (float*)((char*)d_ws + aggB);
        hipMemsetAsync(d_ws, 0, aggB + degB, stream);
    } else {
        // fallback: accumulate directly in d_out (same size as agg), deg in ws
        agg = out;
        deg = (float*)d_ws;
        hipMemsetAsync(out,  0, aggB, stream);
        hipMemsetAsync(d_ws, 0, degB, stream);
    }

    k_scatter<<<(E + 3) / 4, 256, 0, stream>>>(x, src, dst, agg, deg, E);
    k_combine<<<1024,        256, 0, stream>>>(x, agg, deg, Wr, Wl, bl, out, N);
}

// Round 3
// 256.179 us; speedup vs baseline: 3.8024x; 3.8024x over previous
//
#include <hip/hip_runtime.h>
#include <hip/hip_bf16.h>

// ---------- bf16 helpers (weights-in-LDS packing only) ----------
static __device__ __forceinline__ float bflo2f(unsigned int w) {
    union { unsigned int u; float f; } c; c.u = w << 16; return c.f;
}
static __device__ __forceinline__ float bfhi2f(unsigned int w) {
    union { unsigned int u; float f; } c; c.u = w & 0xffff0000u; return c.f;
}
static __device__ __forceinline__ unsigned int f2bf(float f) {
    union { float f; unsigned int u; } c; c.f = f;
    unsigned int u = c.u;
    u = u + 0x7fffu + ((u >> 16) & 1u);   // round-to-nearest-even
    return u >> 16;
}

// ======================= CSR build =======================

// histogram of dst
__global__ __launch_bounds__(256) void k_hist(
        const int* __restrict__ dst, int* __restrict__ cnt, int E)
{
    int e = blockIdx.x * 256 + threadIdx.x;
    if (e < E) atomicAdd(&cnt[dst[e]], 1);
}

// pass 1: per-block inclusive scan of cnt -> block-local exclusive in off[], block sums
__global__ __launch_bounds__(1024) void k_scan1(
        const int* __restrict__ cnt, int* __restrict__ off,
        int* __restrict__ bsum, int N)
{
    __shared__ int sh[1024];
    int t = threadIdx.x;
    int i = blockIdx.x * 1024 + t;
    int v = (i < N) ? cnt[i] : 0;
    sh[t] = v;
    __syncthreads();
    #pragma unroll
    for (int d = 1; d < 1024; d <<= 1) {
        int y = (t >= d) ? sh[t - d] : 0;
        __syncthreads();
        sh[t] += y;
        __syncthreads();
    }
    int incl = sh[t];
    if (i < N) off[i] = incl - v;                 // block-local exclusive
    if (t == 1023) bsum[blockIdx.x] = incl;       // block total
}

// pass 2: scan block sums (nb <= 1024), write off[N]=E
__global__ __launch_bounds__(1024) void k_scan2(
        const int* __restrict__ bsum, int* __restrict__ boff,
        int* __restrict__ off, int nb, int N, int E)
{
    __shared__ int sh[1024];
    int t = threadIdx.x;
    int v = (t < nb) ? bsum[t] : 0;
    sh[t] = v;
    __syncthreads();
    #pragma unroll
    for (int d = 1; d < 1024; d <<= 1) {
        int y = (t >= d) ? sh[t - d] : 0;
        __syncthreads();
        sh[t] += y;
        __syncthreads();
    }
    if (t < nb) boff[t] = sh[t] - v;              // exclusive
    if (t == 0) off[N] = E;
}

// pass 3: add block offsets, make cursor copy
__global__ __launch_bounds__(1024) void k_scan3(
        int* __restrict__ off, int* __restrict__ cur,
        const int* __restrict__ boff, int N)
{
    int i = blockIdx.x * 1024 + threadIdx.x;
    if (i < N) {
        int v = off[i] + boff[blockIdx.x];
        off[i] = v;
        cur[i] = v;
    }
}

// scatter src ids into dst-sorted order
__global__ __launch_bounds__(256) void k_permute(
        const int* __restrict__ src, const int* __restrict__ dst,
        int* __restrict__ cur, int* __restrict__ srcS, int E)
{
    int e = blockIdx.x * 256 + threadIdx.x;
    if (e < E) {
        int d = dst[e];
        int p = atomicAdd(&cur[d], 1);
        srcS[p] = src[e];
    }
}

// ---------- gather: one wave per dst node; mean of neighbor rows ----------
__global__ __launch_bounds__(256) void k_gather(
        const float* __restrict__ x, const int* __restrict__ srcS,
        const int* __restrict__ off, float* a, int N)
{
    int d    = blockIdx.x * 4 + (threadIdx.x >> 6);
    int lane = threadIdx.x & 63;
    if (d >= N) return;
    int n0 = off[d], n1 = off[d + 1];
    const float2* x2 = (const float2*)x;
    float ax0 = 0.f, ay0 = 0.f, ax1 = 0.f, ay1 = 0.f;
    int p = n0;
    for (; p + 2 <= n1; p += 2) {                 // 2 edges in flight
        int s0 = srcS[p], s1 = srcS[p + 1];
        float2 v0 = x2[(size_t)s0 * 64 + lane];
        float2 v1 = x2[(size_t)s1 * 64 + lane];
        ax0 += v0.x; ay0 += v0.y;
        ax1 += v1.x; ay1 += v1.y;
    }
    if (p < n1) {
        int s = srcS[p];
        float2 v = x2[(size_t)s * 64 + lane];
        ax0 += v.x; ay0 += v.y;
    }
    int n = n1 - n0;
    float inv = 1.0f / (float)max(n, 1);
    float2 r; r.x = (ax0 + ax1) * inv; r.y = (ay0 + ay1) * inv;
    ((float2*)a)[(size_t)d * 64 + lane] = r;
}

// ---------- combine: out[i] = x[i]@Wr^T + a[i]@Wl^T + bl ----------
// LDS: WT4[g][l] (uint4, 64 KiB) packs k=4g..4g+3 as bf16 pairs {W[l][k],W[l+64][k]}.
//   g<32 -> Wr (pairs with x), g>=32 -> Wl (pairs with a).
// One wave handles 2 rows; lane owns h=lane and h=lane+64 (4 accumulators).
// ds_read_b128: lane l reads 16B at l*16 -> conflict-free contiguous pattern.
// NOTE: a may alias out (ws fallback): each row pair is read fully (loop) before
// its out rows are written, by its single owning wave -> safe; no __restrict__.
__global__ __launch_bounds__(256) void k_combine(
        const float* __restrict__ x, const float* a,
        const float* __restrict__ Wr, const float* __restrict__ Wl,
        const float* __restrict__ bl,
        float* out, int N)
{
    __shared__ uint4 WT4[64][64];                 // 65536 B
    for (int idx = threadIdx.x; idx < 64 * 64; idx += 256) {
        int g = idx >> 6, l = idx & 63;
        uint4 wv;
        unsigned int* wp = &wv.x;
        #pragma unroll
        for (int kk = 0; kk < 4; ++kk) {
            int k = g * 4 + kk;
            const float* Wsrc = (k < 128) ? Wr : Wl;
            int km = k & 127;
            unsigned int lo = f2bf(Wsrc[(size_t)l * 128 + km]);
            unsigned int hi = f2bf(Wsrc[(size_t)(l + 64) * 128 + km]);
            wp[kk] = lo | (hi << 16);
        }
        WT4[g][l] = wv;
    }
    __syncthreads();

    int wid = threadIdx.x >> 6, lane = threadIdx.x & 63;
    float b0 = bl[lane];
    float b1 = bl[lane + 64];
    int npair = (N + 1) >> 1;

    for (int pi = blockIdx.x * 4 + wid; pi < npair; pi += gridDim.x * 4) {
        int r0 = pi * 2;
        int r1 = r0 + 1;
        bool has1 = (r1 < N);
        const float4* x0 = (const float4*)(x + (size_t)r0 * 128);
        const float4* x1 = (const float4*)(x + (size_t)(has1 ? r1 : r0) * 128);
        const float4* a0 = (const float4*)(a + (size_t)r0 * 128);
        const float4* a1 = (const float4*)(a + (size_t)(has1 ? r1 : r0) * 128);
        float acc00 = b0, acc01 = b1, acc10 = b0, acc11 = b1;

        #pragma unroll 8
        for (int c = 0; c < 32; ++c) {            // K half 1: x with Wr
            uint4 w4 = WT4[c][lane];
            float4 q0 = x0[c];
            float4 q1 = x1[c];
            #pragma unroll
            for (int j = 0; j < 4; ++j) {
                unsigned int w = (&w4.x)[j];
                float wl = bflo2f(w), wh = bfhi2f(w);
                float f0 = (&q0.x)[j], f1 = (&q1.x)[j];
                acc00 = fmaf(f0, wl, acc00);
                acc01 = fmaf(f0, wh, acc01);
                acc10 = fmaf(f1, wl, acc10);
                acc11 = fmaf(f1, wh, acc11);
            }
        }
        #pragma unroll 8
        for (int c = 0; c < 32; ++c) {            // K half 2: mean(agg) with Wl
            uint4 w4 = WT4[c + 32][lane];
            float4 q0 = a0[c];
            float4 q1 = a1[c];
            #pragma unroll
            for (int j = 0; j < 4; ++j) {
                unsigned int w = (&w4.x)[j];
                float wl = bflo2f(w), wh = bfhi2f(w);
                float f0 = (&q0.x)[j], f1 = (&q1.x)[j];
                acc00 = fmaf(f0, wl, acc00);
                acc01 = fmaf(f0, wh, acc01);
                acc10 = fmaf(f1, wl, acc10);
                acc11 = fmaf(f1, wh, acc11);
            }
        }
        out[(size_t)r0 * 128 + lane]      = acc00;
        out[(size_t)r0 * 128 + lane + 64] = acc01;
        if (has1) {
            out[(size_t)r1 * 128 + lane]      = acc10;
            out[(size_t)r1 * 128 + lane + 64] = acc11;
        }
    }
}

// ---------- legacy fallback (tiny ws): atomic scatter ----------
__global__ __launch_bounds__(256) void k_scatter_legacy(
        const float* __restrict__ x,
        const int* __restrict__ src, const int* __restrict__ dst,
        float* __restrict__ agg, float* __restrict__ deg, int E)
{
    int e    = (int)((blockIdx.x * 256u + threadIdx.x) >> 6);
    int lane = threadIdx.x & 63;
    if (e >= E) return;
    int s = src[e];
    int d = dst[e];
    float2 v = ((const float2*)(x + (size_t)s * 128u))[lane];
    float* ar = agg + (size_t)d * 128u;
    unsafeAtomicAdd(ar + 2 * lane,     v.x);
    unsafeAtomicAdd(ar + 2 * lane + 1, v.y);
    if (lane == 0) unsafeAtomicAdd(deg + d, 1.0f);
}

__global__ __launch_bounds__(256) void k_finalize_legacy(
        float* agg, const float* __restrict__ deg, int N)
{
    int t = blockIdx.x * 256 + threadIdx.x;
    if (t >= N * 32) return;
    int node = t >> 5;
    float inv = 1.0f / fmaxf(deg[node], 1.0f);
    float4 v = ((const float4*)agg)[t];
    v.x *= inv; v.y *= inv; v.z *= inv; v.w *= inv;
    ((float4*)agg)[t] = v;
}

extern "C" void kernel_launch(void* const* d_in, const int* in_sizes, int n_in,
                              void* d_out, int out_size, void* d_ws, size_t ws_size,
                              hipStream_t stream)
{
    const float* x  = (const float*)d_in[0];
    const int*   ei = (const int*)d_in[1];
    const float* Wl = (const float*)d_in[2];
    const float* bl = (const float*)d_in[3];
    const float* Wr = (const float*)d_in[4];
    float*      out = (float*)d_out;

    int N = in_sizes[0] / 128;
    int E = in_sizes[1] / 2;
    const int* src = ei;          // edge_index[0] = source nodes (j)
    const int* dst = ei + E;      // edge_index[1] = destination nodes (i)

    int nb = (N + 1023) / 1024;
    size_t aB = (size_t)N * 128 * 4;

    // ws layout: cnt[N] off[N+1] cur[N] bsum[nb] boff[nb] srcS[E] | a[N*128]
    size_t nInts = (size_t)N * 3 + 1 + 2 * (size_t)nb + (size_t)E;
    size_t intsB = ((nInts * 4) + 255) & ~(size_t)255;   // align a to 256B

    if (ws_size >= intsB && nb <= 1024) {
        int* cnt  = (int*)d_ws;
        int* off  = cnt + N;
        int* cur  = off + N + 1;
        int* bsum = cur + N;
        int* boff = bsum + nb;
        int* srcS = boff + nb;
        float* a = (ws_size >= intsB + aB) ? (float*)((char*)d_ws + intsB) : out;

        hipMemsetAsync(cnt, 0, (size_t)N * 4, stream);
        k_hist   <<<(E + 255) / 256, 256, 0, stream>>>(dst, cnt, E);
        k_scan1  <<<nb, 1024, 0, stream>>>(cnt, off, bsum, N);
        k_scan2  <<<1,  1024, 0, stream>>>(bsum, boff, off, nb, N, E);
        k_scan3  <<<nb, 1024, 0, stream>>>(off, cur, boff, N);
        k_permute<<<(E + 255) / 256, 256, 0, stream>>>(src, dst, cur, srcS, E);
        k_gather <<<(N + 3) / 4,     256, 0, stream>>>(x, srcS, off, a, N);
        k_combine<<<1024,            256, 0, stream>>>(x, a, Wr, Wl, bl, out, N);
    } else {
        // legacy atomic path: agg in out, deg (N f32) in ws
        float* agg = out;
        float* deg = (float*)d_ws;
        hipMemsetAsync(out,  0, aB, stream);
        hipMemsetAsync(deg,  0, (size_t)N * 4, stream);
        k_scatter_legacy <<<(E + 3) / 4, 256, 0, stream>>>(x, src, dst, agg, deg, E);
        k_finalize_legacy<<<(N * 32 + 255) / 256, 256, 0, stream>>>(agg, deg, N);
        k_combine<<<1024, 256, 0, stream>>>(x, agg, Wr, Wl, bl, out, N);
    }
}

// Round 4
// 155.261 us; speedup vs baseline: 6.2739x; 1.6500x over previous
//
#include <hip/hip_runtime.h>
#include <hip/hip_bf16.h>

using f32x4 = __attribute__((ext_vector_type(4))) float;
using s16x8 = __attribute__((ext_vector_type(8))) short;   // 8 bf16 (4 VGPRs)

// ---------- bf16 helpers ----------
static __device__ __forceinline__ float bflo2f(unsigned int w) {
    union { unsigned int u; float f; } c; c.u = w << 16; return c.f;
}
static __device__ __forceinline__ float bfhi2f(unsigned int w) {
    union { unsigned int u; float f; } c; c.u = w & 0xffff0000u; return c.f;
}
static __device__ __forceinline__ unsigned int f2bf(float f) {
    union { float f; unsigned int u; } c; c.f = f;
    unsigned int u = c.u;
    u = u + 0x7fffu + ((u >> 16) & 1u);   // round-to-nearest-even
    return u >> 16;
}

// ======================= CSR build =======================

__global__ __launch_bounds__(256) void k_hist(
        const int* __restrict__ dst, int* __restrict__ cnt, int E)
{
    int e = blockIdx.x * 256 + threadIdx.x;
    if (e < E) atomicAdd(&cnt[dst[e]], 1);
}

__global__ __launch_bounds__(1024) void k_scan1(
        const int* __restrict__ cnt, int* __restrict__ off,
        int* __restrict__ bsum, int N)
{
    __shared__ int sh[1024];
    int t = threadIdx.x;
    int i = blockIdx.x * 1024 + t;
    int v = (i < N) ? cnt[i] : 0;
    sh[t] = v;
    __syncthreads();
    #pragma unroll
    for (int d = 1; d < 1024; d <<= 1) {
        int y = (t >= d) ? sh[t - d] : 0;
        __syncthreads();
        sh[t] += y;
        __syncthreads();
    }
    int incl = sh[t];
    if (i < N) off[i] = incl - v;
    if (t == 1023) bsum[blockIdx.x] = incl;
}

__global__ __launch_bounds__(1024) void k_scan2(
        const int* __restrict__ bsum, int* __restrict__ boff,
        int* __restrict__ off, int nb, int N, int E)
{
    __shared__ int sh[1024];
    int t = threadIdx.x;
    int v = (t < nb) ? bsum[t] : 0;
    sh[t] = v;
    __syncthreads();
    #pragma unroll
    for (int d = 1; d < 1024; d <<= 1) {
        int y = (t >= d) ? sh[t - d] : 0;
        __syncthreads();
        sh[t] += y;
        __syncthreads();
    }
    if (t < nb) boff[t] = sh[t] - v;
    if (t == 0) off[N] = E;
}

__global__ __launch_bounds__(1024) void k_scan3(
        int* __restrict__ off, int* __restrict__ cur,
        const int* __restrict__ boff, int N)
{
    int i = blockIdx.x * 1024 + threadIdx.x;
    if (i < N) {
        int v = off[i] + boff[blockIdx.x];
        off[i] = v;
        cur[i] = v;
    }
}

__global__ __launch_bounds__(256) void k_permute(
        const int* __restrict__ src, const int* __restrict__ dst,
        int* __restrict__ cur, int* __restrict__ srcS, int E)
{
    int e = blockIdx.x * 256 + threadIdx.x;
    if (e < E) {
        int d = dst[e];
        int p = atomicAdd(&cur[d], 1);
        srcS[p] = src[e];
    }
}

// ---------- convert x (f32) -> xb (bf16) ----------
__global__ __launch_bounds__(256) void k_convert(
        const float* __restrict__ x, unsigned short* __restrict__ xb, int n4)
{
    int t = blockIdx.x * 256 + threadIdx.x;
    if (t >= n4) return;
    float4 v = ((const float4*)x)[t];
    ushort4 o;
    o.x = (unsigned short)f2bf(v.x);
    o.y = (unsigned short)f2bf(v.y);
    o.z = (unsigned short)f2bf(v.z);
    o.w = (unsigned short)f2bf(v.w);
    ((ushort4*)xb)[t] = o;
}

// ---------- gather: one wave per dst node; bf16 mean of neighbor rows ----------
__global__ __launch_bounds__(256) void k_gather_bf16(
        const float* __restrict__ x, const int* __restrict__ srcS,
        const int* __restrict__ off, unsigned short* __restrict__ ab, int N)
{
    int d    = blockIdx.x * 4 + (threadIdx.x >> 6);
    int lane = threadIdx.x & 63;
    if (d >= N) return;
    int n0 = off[d], n1 = off[d + 1];
    const float2* x2 = (const float2*)x;
    float ax0 = 0.f, ay0 = 0.f, ax1 = 0.f, ay1 = 0.f;
    int p = n0;
    for (; p + 2 <= n1; p += 2) {
        int s0 = srcS[p], s1 = srcS[p + 1];
        float2 v0 = x2[(size_t)s0 * 64 + lane];
        float2 v1 = x2[(size_t)s1 * 64 + lane];
        ax0 += v0.x; ay0 += v0.y;
        ax1 += v1.x; ay1 += v1.y;
    }
    if (p < n1) {
        int s = srcS[p];
        float2 v = x2[(size_t)s * 64 + lane];
        ax0 += v.x; ay0 += v.y;
    }
    int n = n1 - n0;
    float inv = 1.0f / (float)max(n, 1);
    unsigned int pk = f2bf((ax0 + ax1) * inv) | (f2bf((ay0 + ay1) * inv) << 16);
    ((unsigned int*)ab)[(size_t)d * 64 + lane] = pk;
}

// ---------- MFMA combine: out = [xb|ab] @ [Wr|Wl]^T + bl ----------
// B staged frag-ordered in LDS (64 KiB): Bf[nt*8+ks][lane] = short8 of
//   B[k][col], k = ks*32 + (lane>>4)*8 + i, col = nt*16 + (lane&15)
//   (k<128 -> Wr[col][k], k>=128 -> Wl[col][k-128])
// Per wave: 16 rows x 128 cols; A-frag row = lane&15, k-slice = (lane>>4)*8.
// D layout (m89): row = (lane>>4)*4 + i, col = lane&15.
__global__ __launch_bounds__(256) void k_combine_mfma(
        const unsigned short* __restrict__ xb, const unsigned short* __restrict__ ab,
        const float* __restrict__ Wr, const float* __restrict__ Wl,
        const float* __restrict__ bl,
        float* __restrict__ out, int N, int T)
{
    __shared__ s16x8 Bf[64][64];                  // 65536 B
    int t = threadIdx.x;
    for (int s = t; s < 4096; s += 256) {
        int f  = s >> 6, il = s & 63;
        int nt = f >> 3, ks = f & 7;
        int col = nt * 16 + (il & 15);
        int k   = ks * 32 + (il >> 4) * 8;        // 0..255
        const float* Wsrc = (k < 128) ? Wr : Wl;
        int k0 = k & 127;
        const float4* wp = (const float4*)(Wsrc + (size_t)col * 128 + k0);
        float4 w0 = wp[0], w1 = wp[1];
        s16x8 v;
        v[0] = (short)f2bf(w0.x); v[1] = (short)f2bf(w0.y);
        v[2] = (short)f2bf(w0.z); v[3] = (short)f2bf(w0.w);
        v[4] = (short)f2bf(w1.x); v[5] = (short)f2bf(w1.y);
        v[6] = (short)f2bf(w1.z); v[7] = (short)f2bf(w1.w);
        Bf[f][il] = v;
    }
    __syncthreads();

    int wid = t >> 6, l = t & 63;
    int lr = l & 15, lg = l >> 4;
    float bias[8];
    #pragma unroll
    for (int nt = 0; nt < 8; ++nt) bias[nt] = bl[nt * 16 + lr];

    for (int tile = blockIdx.x; tile < T; tile += gridDim.x) {
        int rowbase = tile * 64 + wid * 16;
        int arow = min(rowbase + lr, N - 1);      // clamp for tail tile
        const s16x8* xr = (const s16x8*)(xb + (size_t)arow * 128);
        const s16x8* ar = (const s16x8*)(ab + (size_t)arow * 128);
        s16x8 af[8];
        #pragma unroll
        for (int ks = 0; ks < 4; ++ks) af[ks]     = xr[ks * 4 + lg];
        #pragma unroll
        for (int ks = 0; ks < 4; ++ks) af[4 + ks] = ar[ks * 4 + lg];

        f32x4 acc[8];
        #pragma unroll
        for (int nt = 0; nt < 8; ++nt) {
            float b = bias[nt];
            acc[nt] = (f32x4){b, b, b, b};
        }

        #pragma unroll
        for (int ks = 0; ks < 8; ++ks)
            #pragma unroll
            for (int nt = 0; nt < 8; ++nt)
                acc[nt] = __builtin_amdgcn_mfma_f32_16x16x32_bf16(
                              af[ks], Bf[nt * 8 + ks][l], acc[nt], 0, 0, 0);

        #pragma unroll
        for (int i = 0; i < 4; ++i) {
            int row = rowbase + lg * 4 + i;
            if (row < N) {
                float* op = out + (size_t)row * 128 + lr;
                #pragma unroll
                for (int nt = 0; nt < 8; ++nt) op[nt * 16] = acc[nt][i];
            }
        }
    }
}

// ======================= fallback path (small ws) =======================

__global__ __launch_bounds__(256) void k_gather_f32(
        const float* __restrict__ x, const int* __restrict__ srcS,
        const int* __restrict__ off, float* a, int N)
{
    int d    = blockIdx.x * 4 + (threadIdx.x >> 6);
    int lane = threadIdx.x & 63;
    if (d >= N) return;
    int n0 = off[d], n1 = off[d + 1];
    const float2* x2 = (const float2*)x;
    float ax = 0.f, ay = 0.f;
    for (int p = n0; p < n1; ++p) {
        int s = srcS[p];
        float2 v = x2[(size_t)s * 64 + lane];
        ax += v.x; ay += v.y;
    }
    float inv = 1.0f / (float)max(n1 - n0, 1);
    float2 r; r.x = ax * inv; r.y = ay * inv;
    ((float2*)a)[(size_t)d * 64 + lane] = r;
}

__global__ __launch_bounds__(256) void k_combine_valu(
        const float* __restrict__ x, const float* a,
        const float* __restrict__ Wr, const float* __restrict__ Wl,
        const float* __restrict__ bl,
        float* out, int N)
{
    __shared__ uint4 WT4[64][64];
    for (int idx = threadIdx.x; idx < 64 * 64; idx += 256) {
        int g = idx >> 6, l = idx & 63;
        uint4 wv;
        unsigned int* wp = &wv.x;
        #pragma unroll
        for (int kk = 0; kk < 4; ++kk) {
            int k = g * 4 + kk;
            const float* Wsrc = (k < 128) ? Wr : Wl;
            int km = k & 127;
            unsigned int lo = f2bf(Wsrc[(size_t)l * 128 + km]);
            unsigned int hi = f2bf(Wsrc[(size_t)(l + 64) * 128 + km]);
            wp[kk] = lo | (hi << 16);
        }
        WT4[g][l] = wv;
    }
    __syncthreads();

    int wid = threadIdx.x >> 6, lane = threadIdx.x & 63;
    float b0 = bl[lane], b1 = bl[lane + 64];
    for (int row = blockIdx.x * 4 + wid; row < N; row += gridDim.x * 4) {
        const float4* xr = (const float4*)(x + (size_t)row * 128);
        const float4* ar = (const float4*)(a + (size_t)row * 128);
        float acc0 = b0, acc1 = b1;
        #pragma unroll 8
        for (int c = 0; c < 32; ++c) {
            uint4 w4 = WT4[c][lane];
            float4 q = xr[c];
            #pragma unroll
            for (int j = 0; j < 4; ++j) {
                unsigned int w = (&w4.x)[j];
                float f = (&q.x)[j];
                acc0 = fmaf(f, bflo2f(w), acc0);
                acc1 = fmaf(f, bfhi2f(w), acc1);
            }
        }
        #pragma unroll 8
        for (int c = 0; c < 32; ++c) {
            uint4 w4 = WT4[c + 32][lane];
            float4 q = ar[c];
            #pragma unroll
            for (int j = 0; j < 4; ++j) {
                unsigned int w = (&w4.x)[j];
                float f = (&q.x)[j];
                acc0 = fmaf(f, bflo2f(w), acc0);
                acc1 = fmaf(f, bfhi2f(w), acc1);
            }
        }
        out[(size_t)row * 128 + lane]      = acc0;
        out[(size_t)row * 128 + lane + 64] = acc1;
    }
}

__global__ __launch_bounds__(256) void k_scatter_legacy(
        const float* __restrict__ x,
        const int* __restrict__ src, const int* __restrict__ dst,
        float* __restrict__ agg, float* __restrict__ deg, int E)
{
    int e    = (int)((blockIdx.x * 256u + threadIdx.x) >> 6);
    int lane = threadIdx.x & 63;
    if (e >= E) return;
    int s = src[e];
    int d = dst[e];
    float2 v = ((const float2*)(x + (size_t)s * 128u))[lane];
    float* ar = agg + (size_t)d * 128u;
    unsafeAtomicAdd(ar + 2 * lane,     v.x);
    unsafeAtomicAdd(ar + 2 * lane + 1, v.y);
    if (lane == 0) unsafeAtomicAdd(deg + d, 1.0f);
}

__global__ __launch_bounds__(256) void k_finalize_legacy(
        float* agg, const float* __restrict__ deg, int N)
{
    int t = blockIdx.x * 256 + threadIdx.x;
    if (t >= N * 32) return;
    int node = t >> 5;
    float inv = 1.0f / fmaxf(deg[node], 1.0f);
    float4 v = ((const float4*)agg)[t];
    v.x *= inv; v.y *= inv; v.z *= inv; v.w *= inv;
    ((float4*)agg)[t] = v;
}

// ======================= launch =======================

extern "C" void kernel_launch(void* const* d_in, const int* in_sizes, int n_in,
                              void* d_out, int out_size, void* d_ws, size_t ws_size,
                              hipStream_t stream)
{
    const float* x  = (const float*)d_in[0];
    const int*   ei = (const int*)d_in[1];
    const float* Wl = (const float*)d_in[2];
    const float* bl = (const float*)d_in[3];
    const float* Wr = (const float*)d_in[4];
    float*      out = (float*)d_out;

    int N = in_sizes[0] / 128;
    int E = in_sizes[1] / 2;
    const int* src = ei;          // edge_index[0] = source nodes (j)
    const int* dst = ei + E;      // edge_index[1] = destination nodes (i)

    int nb = (N + 1023) / 1024;
    size_t aB  = (size_t)N * 128 * 4;              // f32 row block
    size_t bfB = (size_t)N * 128 * 2;              // bf16 row block

    // ws layout: cnt[N] off[N+1] cur[N] bsum[nb] boff[nb] srcS[E] | xb | ab
    size_t nInts = (size_t)N * 3 + 1 + 2 * (size_t)nb + (size_t)E;
    size_t intsB = ((nInts * 4) + 255) & ~(size_t)255;

    if (ws_size >= intsB + 2 * bfB && nb <= 1024) {
        // -------- MFMA path --------
        int* cnt  = (int*)d_ws;
        int* off  = cnt + N;
        int* cur  = off + N + 1;
        int* bsum = cur + N;
        int* boff = bsum + nb;
        int* srcS = boff + nb;
        unsigned short* xb = (unsigned short*)((char*)d_ws + intsB);
        unsigned short* ab = xb + (size_t)N * 128;

        hipMemsetAsync(cnt, 0, (size_t)N * 4, stream);
        k_hist    <<<(E + 255) / 256, 256, 0, stream>>>(dst, cnt, E);
        k_scan1   <<<nb, 1024, 0, stream>>>(cnt, off, bsum, N);
        k_scan2   <<<1,  1024, 0, stream>>>(bsum, boff, off, nb, N, E);
        k_scan3   <<<nb, 1024, 0, stream>>>(off, cur, boff, N);
        k_permute <<<(E + 255) / 256, 256, 0, stream>>>(src, dst, cur, srcS, E);
        k_convert <<<(N * 32 + 255) / 256, 256, 0, stream>>>(x, xb, N * 32);
        k_gather_bf16<<<(N + 3) / 4, 256, 0, stream>>>(x, srcS, off, ab, N);
        int T = (N + 63) / 64;
        k_combine_mfma<<<512, 256, 0, stream>>>(xb, ab, Wr, Wl, bl, out, N, T);
    } else if (ws_size >= intsB && nb <= 1024) {
        // -------- CSR + VALU path (a aliases out) --------
        int* cnt  = (int*)d_ws;
        int* off  = cnt + N;
        int* cur  = off + N + 1;
        int* bsum = cur + N;
        int* boff = bsum + nb;
        int* srcS = boff + nb;
        float* a = (ws_size >= intsB + aB) ? (float*)((char*)d_ws + intsB) : out;

        hipMemsetAsync(cnt, 0, (size_t)N * 4, stream);
        k_hist    <<<(E + 255) / 256, 256, 0, stream>>>(dst, cnt, E);
        k_scan1   <<<nb, 1024, 0, stream>>>(cnt, off, bsum, N);
        k_scan2   <<<1,  1024, 0, stream>>>(bsum, boff, off, nb, N, E);
        k_scan3   <<<nb, 1024, 0, stream>>>(off, cur, boff, N);
        k_permute <<<(E + 255) / 256, 256, 0, stream>>>(src, dst, cur, srcS, E);
        k_gather_f32<<<(N + 3) / 4, 256, 0, stream>>>(x, srcS, off, a, N);
        k_combine_valu<<<1024, 256, 0, stream>>>(x, a, Wr, Wl, bl, out, N);
    } else {
        // -------- legacy atomic path --------
        float* agg = out;
        float* deg = (float*)d_ws;
        hipMemsetAsync(out, 0, aB, stream);
        hipMemsetAsync(deg, 0, (size_t)N * 4, stream);
        k_scatter_legacy <<<(E + 3) / 4, 256, 0, stream>>>(x, src, dst, agg, deg, E);
        k_finalize_legacy<<<(N * 32 + 255) / 256, 256, 0, stream>>>(agg, deg, N);
        k_combine_valu<<<1024, 256, 0, stream>>>(x, agg, Wr, Wl, bl, out, N);
    }
}

// Round 5
// 135.027 us; speedup vs baseline: 7.2141x; 1.1499x over previous
//
#include <hip/hip_runtime.h>
#include <hip/hip_bf16.h>

using f32x4 = __attribute__((ext_vector_type(4))) float;
using s16x8 = __attribute__((ext_vector_type(8))) short;   // 8 bf16 (4 VGPRs)

// ---------- bf16 helpers ----------
static __device__ __forceinline__ float bflo2f(unsigned int w) {
    union { unsigned int u; float f; } c; c.u = w << 16; return c.f;
}
static __device__ __forceinline__ float bfhi2f(unsigned int w) {
    union { unsigned int u; float f; } c; c.u = w & 0xffff0000u; return c.f;
}
static __device__ __forceinline__ unsigned int f2bf(float f) {
    union { float f; unsigned int u; } c; c.f = f;
    unsigned int u = c.u;
    u = u + 0x7fffu + ((u >> 16) & 1u);   // round-to-nearest-even
    return u >> 16;
}

// ======================= CSR build =======================

__global__ __launch_bounds__(256) void k_hist(
        const int* __restrict__ dst, int* __restrict__ cnt, int E)
{
    int e = blockIdx.x * 256 + threadIdx.x;
    if (e < E) atomicAdd(&cnt[dst[e]], 1);
}

__global__ __launch_bounds__(1024) void k_scan1(
        const int* __restrict__ cnt, int* __restrict__ off,
        int* __restrict__ bsum, int N)
{
    __shared__ int sh[1024];
    int t = threadIdx.x;
    int i = blockIdx.x * 1024 + t;
    int v = (i < N) ? cnt[i] : 0;
    sh[t] = v;
    __syncthreads();
    #pragma unroll
    for (int d = 1; d < 1024; d <<= 1) {
        int y = (t >= d) ? sh[t - d] : 0;
        __syncthreads();
        sh[t] += y;
        __syncthreads();
    }
    int incl = sh[t];
    if (i < N) off[i] = incl - v;                 // block-local exclusive
    if (t == 1023) bsum[blockIdx.x] = incl;
}

__global__ __launch_bounds__(1024) void k_scan2(
        const int* __restrict__ bsum, int* __restrict__ boff,
        int* __restrict__ off, int nb, int N, int E)
{
    __shared__ int sh[1024];
    int t = threadIdx.x;
    int v = (t < nb) ? bsum[t] : 0;
    sh[t] = v;
    __syncthreads();
    #pragma unroll
    for (int d = 1; d < 1024; d <<= 1) {
        int y = (t >= d) ? sh[t - d] : 0;
        __syncthreads();
        sh[t] += y;
        __syncthreads();
    }
    if (t < nb) boff[t] = sh[t] - v;
    if (t == 0) off[N] = E;
}

__global__ __launch_bounds__(1024) void k_scan3(
        int* __restrict__ off, const int* __restrict__ boff, int N)
{
    int i = blockIdx.x * 1024 + threadIdx.x;
    if (i < N) off[i] += boff[blockIdx.x];
}

// permute bumps off[d] itself: post-permute off[d] == end of segment d,
// so segment d = [ d? off[d-1] : 0 , off[d] ).
__global__ __launch_bounds__(256) void k_permute(
        const int* __restrict__ src, const int* __restrict__ dst,
        int* __restrict__ off, int* __restrict__ srcS, int E)
{
    int e = blockIdx.x * 256 + threadIdx.x;
    if (e < E) {
        int d = dst[e];
        int p = atomicAdd(&off[d], 1);
        srcS[p] = src[e];
    }
}

// ---------- convert x -> xb (bf16) + prep weight fragments ----------
// Blocks [0,nxb): x conversion. Blocks [nxb, nxb+16): wprep[s], s in [0,4096):
//   f = s>>6 (frag id: nt*8+ks), il = s&63 (lane);
//   short8 of B[k][col], k = ks*32+(il>>4)*8+i, col = nt*16+(il&15)
//   (k<128 -> Wr[col][k], else Wl[col][k-128])
__global__ __launch_bounds__(256) void k_convert(
        const float* __restrict__ x, unsigned short* __restrict__ xb,
        const float* __restrict__ Wr, const float* __restrict__ Wl,
        s16x8* __restrict__ wprep, int n4, int nxb)
{
    int b = blockIdx.x;
    if (b < nxb) {
        int t = b * 256 + threadIdx.x;
        if (t >= n4) return;
        float4 v = ((const float4*)x)[t];
        ushort4 o;
        o.x = (unsigned short)f2bf(v.x);
        o.y = (unsigned short)f2bf(v.y);
        o.z = (unsigned short)f2bf(v.z);
        o.w = (unsigned short)f2bf(v.w);
        ((ushort4*)xb)[t] = o;
    } else if (wprep) {
        int s = (b - nxb) * 256 + threadIdx.x;
        if (s >= 4096) return;
        int f = s >> 6, il = s & 63;
        int nt = f >> 3, ks = f & 7;
        int col = nt * 16 + (il & 15);
        int k   = ks * 32 + (il >> 4) * 8;
        const float* Wsrc = (k < 128) ? Wr : Wl;
        int k0 = k & 127;
        const float4* wp = (const float4*)(Wsrc + (size_t)col * 128 + k0);
        float4 w0 = wp[0], w1 = wp[1];
        s16x8 v;
        v[0] = (short)f2bf(w0.x); v[1] = (short)f2bf(w0.y);
        v[2] = (short)f2bf(w0.z); v[3] = (short)f2bf(w0.w);
        v[4] = (short)f2bf(w1.x); v[5] = (short)f2bf(w1.y);
        v[6] = (short)f2bf(w1.z); v[7] = (short)f2bf(w1.w);
        wprep[s] = v;
    }
}

// ---------- gather: one wave per dst node; bf16 mean of neighbor rows ----------
// reads xb rows (256B, one uint = 2 bf16 per lane), 4 edges in flight
__global__ __launch_bounds__(256) void k_gather_bf16(
        const unsigned int* __restrict__ xu, const int* __restrict__ srcS,
        const int* __restrict__ off, unsigned int* __restrict__ ab, int N)
{
    int d    = blockIdx.x * 4 + (threadIdx.x >> 6);
    int lane = threadIdx.x & 63;
    if (d >= N) return;
    int n1 = off[d];
    int n0 = (d > 0) ? off[d - 1] : 0;
    float ax0 = 0.f, ay0 = 0.f, ax1 = 0.f, ay1 = 0.f;
    float ax2 = 0.f, ay2 = 0.f, ax3 = 0.f, ay3 = 0.f;
    int p = n0;
    for (; p + 4 <= n1; p += 4) {
        int s0 = srcS[p],     s1 = srcS[p + 1];
        int s2 = srcS[p + 2], s3 = srcS[p + 3];
        unsigned int v0 = xu[(size_t)s0 * 64 + lane];
        unsigned int v1 = xu[(size_t)s1 * 64 + lane];
        unsigned int v2 = xu[(size_t)s2 * 64 + lane];
        unsigned int v3 = xu[(size_t)s3 * 64 + lane];
        ax0 += bflo2f(v0); ay0 += bfhi2f(v0);
        ax1 += bflo2f(v1); ay1 += bfhi2f(v1);
        ax2 += bflo2f(v2); ay2 += bfhi2f(v2);
        ax3 += bflo2f(v3); ay3 += bfhi2f(v3);
    }
    for (; p < n1; ++p) {
        int s = srcS[p];
        unsigned int v = xu[(size_t)s * 64 + lane];
        ax0 += bflo2f(v); ay0 += bfhi2f(v);
    }
    int n = n1 - n0;
    float inv = 1.0f / (float)max(n, 1);
    unsigned int pk = f2bf((ax0 + ax1 + ax2 + ax3) * inv)
                    | (f2bf((ay0 + ay1 + ay2 + ay3) * inv) << 16);
    ab[(size_t)d * 64 + lane] = pk;
}

// ---------- MFMA combine: out = [xb|ab] @ [Wr|Wl]^T + bl ----------
// B fragments in LDS (64 KiB), copied from wprep (or computed if wprep==null).
// Per wave: 16 rows x 128 cols; A-frag row = lane&15, k-slice = (lane>>4)*8.
// D layout (m89): row = (lane>>4)*4 + i, col = lane&15.
__global__ __launch_bounds__(256) void k_combine_mfma(
        const unsigned short* __restrict__ xb, const unsigned short* __restrict__ ab,
        const s16x8* __restrict__ wprep,
        const float* __restrict__ Wr, const float* __restrict__ Wl,
        const float* __restrict__ bl,
        float* __restrict__ out, int N, int T)
{
    __shared__ s16x8 Bf[64][64];                  // 65536 B
    int t = threadIdx.x;
    if (wprep) {
        const uint4* ws = (const uint4*)wprep;
        uint4* bd = (uint4*)&Bf[0][0];
        for (int s = t; s < 4096; s += 256) bd[s] = ws[s];
    } else {
        for (int s = t; s < 4096; s += 256) {
            int f = s >> 6, il = s & 63;
            int nt = f >> 3, ks = f & 7;
            int col = nt * 16 + (il & 15);
            int k   = ks * 32 + (il >> 4) * 8;
            const float* Wsrc = (k < 128) ? Wr : Wl;
            int k0 = k & 127;
            const float4* wp = (const float4*)(Wsrc + (size_t)col * 128 + k0);
            float4 w0 = wp[0], w1 = wp[1];
            s16x8 v;
            v[0] = (short)f2bf(w0.x); v[1] = (short)f2bf(w0.y);
            v[2] = (short)f2bf(w0.z); v[3] = (short)f2bf(w0.w);
            v[4] = (short)f2bf(w1.x); v[5] = (short)f2bf(w1.y);
            v[6] = (short)f2bf(w1.z); v[7] = (short)f2bf(w1.w);
            Bf[f][il] = v;
        }
    }
    __syncthreads();

    int wid = t >> 6, l = t & 63;
    int lr = l & 15, lg = l >> 4;
    float bias[8];
    #pragma unroll
    for (int nt = 0; nt < 8; ++nt) bias[nt] = bl[nt * 16 + lr];

    for (int tile = blockIdx.x; tile < T; tile += gridDim.x) {
        int rowbase = tile * 64 + wid * 16;
        int arow = min(rowbase + lr, N - 1);      // clamp for tail tile
        const s16x8* xr = (const s16x8*)(xb + (size_t)arow * 128);
        const s16x8* ar = (const s16x8*)(ab + (size_t)arow * 128);
        s16x8 af[8];
        #pragma unroll
        for (int ks = 0; ks < 4; ++ks) af[ks]     = xr[ks * 4 + lg];
        #pragma unroll
        for (int ks = 0; ks < 4; ++ks) af[4 + ks] = ar[ks * 4 + lg];

        f32x4 acc[8];
        #pragma unroll
        for (int nt = 0; nt < 8; ++nt) {
            float b = bias[nt];
            acc[nt] = (f32x4){b, b, b, b};
        }

        #pragma unroll
        for (int ks = 0; ks < 8; ++ks)
            #pragma unroll
            for (int nt = 0; nt < 8; ++nt)
                acc[nt] = __builtin_amdgcn_mfma_f32_16x16x32_bf16(
                              af[ks], Bf[nt * 8 + ks][l], acc[nt], 0, 0, 0);

        #pragma unroll
        for (int i = 0; i < 4; ++i) {
            int row = rowbase + lg * 4 + i;
            if (row < N) {
                float* op = out + (size_t)row * 128 + lr;
                #pragma unroll
                for (int nt = 0; nt < 8; ++nt) op[nt * 16] = acc[nt][i];
            }
        }
    }
}

// ======================= fallback path (small ws) =======================

__global__ __launch_bounds__(256) void k_gather_f32(
        const float* __restrict__ x, const int* __restrict__ srcS,
        const int* __restrict__ off, float* a, int N)
{
    int d    = blockIdx.x * 4 + (threadIdx.x >> 6);
    int lane = threadIdx.x & 63;
    if (d >= N) return;
    int n1 = off[d];
    int n0 = (d > 0) ? off[d - 1] : 0;
    const float2* x2 = (const float2*)x;
    float ax = 0.f, ay = 0.f;
    for (int p = n0; p < n1; ++p) {
        int s = srcS[p];
        float2 v = x2[(size_t)s * 64 + lane];
        ax += v.x; ay += v.y;
    }
    float inv = 1.0f / (float)max(n1 - n0, 1);
    float2 r; r.x = ax * inv; r.y = ay * inv;
    ((float2*)a)[(size_t)d * 64 + lane] = r;
}

__global__ __launch_bounds__(256) void k_combine_valu(
        const float* __restrict__ x, const float* a,
        const float* __restrict__ Wr, const float* __restrict__ Wl,
        const float* __restrict__ bl,
        float* out, int N)
{
    __shared__ uint4 WT4[64][64];
    for (int idx = threadIdx.x; idx < 64 * 64; idx += 256) {
        int g = idx >> 6, l = idx & 63;
        uint4 wv;
        unsigned int* wp = &wv.x;
        #pragma unroll
        for (int kk = 0; kk < 4; ++kk) {
            int k = g * 4 + kk;
            const float* Wsrc = (k < 128) ? Wr : Wl;
            int km = k & 127;
            unsigned int lo = f2bf(Wsrc[(size_t)l * 128 + km]);
            unsigned int hi = f2bf(Wsrc[(size_t)(l + 64) * 128 + km]);
            wp[kk] = lo | (hi << 16);
        }
        WT4[g][l] = wv;
    }
    __syncthreads();

    int wid = threadIdx.x >> 6, lane = threadIdx.x & 63;
    float b0 = bl[lane], b1 = bl[lane + 64];
    for (int row = blockIdx.x * 4 + wid; row < N; row += gridDim.x * 4) {
        const float4* xr = (const float4*)(x + (size_t)row * 128);
        const float4* ar = (const float4*)(a + (size_t)row * 128);
        float acc0 = b0, acc1 = b1;
        #pragma unroll 8
        for (int c = 0; c < 32; ++c) {
            uint4 w4 = WT4[c][lane];
            float4 q = xr[c];
            #pragma unroll
            for (int j = 0; j < 4; ++j) {
                unsigned int w = (&w4.x)[j];
                float f = (&q.x)[j];
                acc0 = fmaf(f, bflo2f(w), acc0);
                acc1 = fmaf(f, bfhi2f(w), acc1);
            }
        }
        #pragma unroll 8
        for (int c = 0; c < 32; ++c) {
            uint4 w4 = WT4[c + 32][lane];
            float4 q = ar[c];
            #pragma unroll
            for (int j = 0; j < 4; ++j) {
                unsigned int w = (&w4.x)[j];
                float f = (&q.x)[j];
                acc0 = fmaf(f, bflo2f(w), acc0);
                acc1 = fmaf(f, bfhi2f(w), acc1);
            }
        }
        out[(size_t)row * 128 + lane]      = acc0;
        out[(size_t)row * 128 + lane + 64] = acc1;
    }
}

__global__ __launch_bounds__(256) void k_scatter_legacy(
        const float* __restrict__ x,
        const int* __restrict__ src, const int* __restrict__ dst,
        float* __restrict__ agg, float* __restrict__ deg, int E)
{
    int e    = (int)((blockIdx.x * 256u + threadIdx.x) >> 6);
    int lane = threadIdx.x & 63;
    if (e >= E) return;
    int s = src[e];
    int d = dst[e];
    float2 v = ((const float2*)(x + (size_t)s * 128u))[lane];
    float* ar = agg + (size_t)d * 128u;
    unsafeAtomicAdd(ar + 2 * lane,     v.x);
    unsafeAtomicAdd(ar + 2 * lane + 1, v.y);
    if (lane == 0) unsafeAtomicAdd(deg + d, 1.0f);
}

__global__ __launch_bounds__(256) void k_finalize_legacy(
        float* agg, const float* __restrict__ deg, int N)
{
    int t = blockIdx.x * 256 + threadIdx.x;
    if (t >= N * 32) return;
    int node = t >> 5;
    float inv = 1.0f / fmaxf(deg[node], 1.0f);
    float4 v = ((const float4*)agg)[t];
    v.x *= inv; v.y *= inv; v.z *= inv; v.w *= inv;
    ((float4*)agg)[t] = v;
}

// ======================= launch =======================

extern "C" void kernel_launch(void* const* d_in, const int* in_sizes, int n_in,
                              void* d_out, int out_size, void* d_ws, size_t ws_size,
                              hipStream_t stream)
{
    const float* x  = (const float*)d_in[0];
    const int*   ei = (const int*)d_in[1];
    const float* Wl = (const float*)d_in[2];
    const float* bl = (const float*)d_in[3];
    const float* Wr = (const float*)d_in[4];
    float*      out = (float*)d_out;

    int N = in_sizes[0] / 128;
    int E = in_sizes[1] / 2;
    const int* src = ei;          // edge_index[0] = source nodes (j)
    const int* dst = ei + E;      // edge_index[1] = destination nodes (i)

    int nb = (N + 1023) / 1024;
    size_t aB  = (size_t)N * 128 * 4;              // f32 row block
    size_t bfB = (size_t)N * 128 * 2;              // bf16 row block

    // ws: cnt[N] off[N+1] bsum[nb] boff[nb] srcS[E] | xb | ab | wprep(64KB)
    size_t nInts = (size_t)N * 2 + 1 + 2 * (size_t)nb + (size_t)E;
    size_t intsB = ((nInts * 4) + 255) & ~(size_t)255;

    if (ws_size >= intsB + 2 * bfB && nb <= 1024) {
        // -------- MFMA path --------
        int* cnt  = (int*)d_ws;
        int* off  = cnt + N;
        int* bsum = off + N + 1;
        int* boff = bsum + nb;
        int* srcS = boff + nb;
        unsigned short* xb = (unsigned short*)((char*)d_ws + intsB);
        unsigned short* ab = xb + (size_t)N * 128;
        s16x8* wprep = (ws_size >= intsB + 2 * bfB + 65536)
                     ? (s16x8*)((char*)ab + bfB) : nullptr;

        int nxb = (N * 32 + 255) / 256;
        int ncv = nxb + (wprep ? 16 : 0);

        hipMemsetAsync(cnt, 0, (size_t)N * 4, stream);
        k_convert <<<ncv, 256, 0, stream>>>(x, xb, Wr, Wl, wprep, N * 32, nxb);
        k_hist    <<<(E + 255) / 256, 256, 0, stream>>>(dst, cnt, E);
        k_scan1   <<<nb, 1024, 0, stream>>>(cnt, off, bsum, N);
        k_scan2   <<<1,  1024, 0, stream>>>(bsum, boff, off, nb, N, E);
        k_scan3   <<<nb, 1024, 0, stream>>>(off, boff, N);
        k_permute <<<(E + 255) / 256, 256, 0, stream>>>(src, dst, off, srcS, E);
        k_gather_bf16<<<(N + 3) / 4, 256, 0, stream>>>(
                (const unsigned int*)xb, srcS, off, (unsigned int*)ab, N);
        int T = (N + 63) / 64;
        k_combine_mfma<<<512, 256, 0, stream>>>(xb, ab, wprep, Wr, Wl, bl, out, N, T);
    } else if (ws_size >= intsB && nb <= 1024) {
        // -------- CSR + VALU path (a aliases out) --------
        int* cnt  = (int*)d_ws;
        int* off  = cnt + N;
        int* bsum = off + N + 1;
        int* boff = bsum + nb;
        int* srcS = boff + nb;
        float* a = (ws_size >= intsB + aB) ? (float*)((char*)d_ws + intsB) : out;

        hipMemsetAsync(cnt, 0, (size_t)N * 4, stream);
        k_hist    <<<(E + 255) / 256, 256, 0, stream>>>(dst, cnt, E);
        k_scan1   <<<nb, 1024, 0, stream>>>(cnt, off, bsum, N);
        k_scan2   <<<1,  1024, 0, stream>>>(bsum, boff, off, nb, N, E);
        k_scan3   <<<nb, 1024, 0, stream>>>(off, boff, N);
        k_permute <<<(E + 255) / 256, 256, 0, stream>>>(src, dst, off, srcS, E);
        k_gather_f32<<<(N + 3) / 4, 256, 0, stream>>>(x, srcS, off, a, N);
        k_combine_valu<<<1024, 256, 0, stream>>>(x, a, Wr, Wl, bl, out, N);
    } else {
        // -------- legacy atomic path --------
        float* agg = out;
        float* deg = (float*)d_ws;
        hipMemsetAsync(out, 0, aB, stream);
        hipMemsetAsync(deg, 0, (size_t)N * 4, stream);
        k_scatter_legacy <<<(E + 3) / 4, 256, 0, stream>>>(x, src, dst, agg, deg, E);
        k_finalize_legacy<<<(N * 32 + 255) / 256, 256, 0, stream>>>(agg, deg, N);
        k_combine_valu<<<1024, 256, 0, stream>>>(x, agg, Wr, Wl, bl, out, N);
    }
}

// Round 6
// 130.351 us; speedup vs baseline: 7.4729x; 1.0359x over previous
//
#include <hip/hip_runtime.h>
#include <hip/hip_bf16.h>

using f32x4 = __attribute__((ext_vector_type(4))) float;
using s16x8 = __attribute__((ext_vector_type(8))) short;   // 8 bf16 (4 VGPRs)

// ---------- bf16 helpers ----------
static __device__ __forceinline__ float bflo2f(unsigned int w) {
    union { unsigned int u; float f; } c; c.u = w << 16; return c.f;
}
static __device__ __forceinline__ float bfhi2f(unsigned int w) {
    union { unsigned int u; float f; } c; c.u = w & 0xffff0000u; return c.f;
}
static __device__ __forceinline__ unsigned int f2bf(float f) {
    union { float f; unsigned int u; } c; c.f = f;
    unsigned int u = c.u;
    u = u + 0x7fffu + ((u >> 16) & 1u);   // round-to-nearest-even
    return u >> 16;
}

// ======================= CSR build =======================

__global__ __launch_bounds__(256) void k_hist(
        const int* __restrict__ dst, int* __restrict__ cnt, int E)
{
    int e = blockIdx.x * 256 + threadIdx.x;
    if (e < E) atomicAdd(&cnt[dst[e]], 1);
}

__global__ __launch_bounds__(1024) void k_scan1(
        const int* __restrict__ cnt, int* __restrict__ off,
        int* __restrict__ bsum, int N)
{
    __shared__ int sh[1024];
    int t = threadIdx.x;
    int i = blockIdx.x * 1024 + t;
    int v = (i < N) ? cnt[i] : 0;
    sh[t] = v;
    __syncthreads();
    #pragma unroll
    for (int d = 1; d < 1024; d <<= 1) {
        int y = (t >= d) ? sh[t - d] : 0;
        __syncthreads();
        sh[t] += y;
        __syncthreads();
    }
    int incl = sh[t];
    if (i < N) off[i] = incl - v;                 // block-local exclusive
    if (t == 1023) bsum[blockIdx.x] = incl;
}

__global__ __launch_bounds__(1024) void k_scan2(
        const int* __restrict__ bsum, int* __restrict__ boff,
        int* __restrict__ off, int nb, int N, int E)
{
    __shared__ int sh[1024];
    int t = threadIdx.x;
    int v = (t < nb) ? bsum[t] : 0;
    sh[t] = v;
    __syncthreads();
    #pragma unroll
    for (int d = 1; d < 1024; d <<= 1) {
        int y = (t >= d) ? sh[t - d] : 0;
        __syncthreads();
        sh[t] += y;
        __syncthreads();
    }
    if (t < nb) boff[t] = sh[t] - v;
    if (t == 0) off[N] = E;
}

__global__ __launch_bounds__(1024) void k_scan3(
        int* __restrict__ off, const int* __restrict__ boff, int N)
{
    int i = blockIdx.x * 1024 + threadIdx.x;
    if (i < N) off[i] += boff[blockIdx.x];
}

// permute bumps off[d] itself: post-permute off[d] == end of segment d,
// so segment d = [ d? off[d-1] : 0 , off[d] ).
__global__ __launch_bounds__(256) void k_permute(
        const int* __restrict__ src, const int* __restrict__ dst,
        int* __restrict__ off, int* __restrict__ srcS, int E)
{
    int e = blockIdx.x * 256 + threadIdx.x;
    if (e < E) {
        int d = dst[e];
        int p = atomicAdd(&off[d], 1);
        srcS[p] = src[e];
    }
}

// ---------- convert x -> xb (bf16) + prep weight fragments + zero cnt ------
// Blocks [0,nxb): x conversion.
// Blocks [nxb, nxb+16): wprep[s] (frag-ordered weights, see k_combine_mfma).
// Blocks [nxb+16, ...): zero cnt[N] (replaces pathological rocclr fill:
//   hipMemsetAsync(200KB) showed 42.8us in-graph in round-5 profile).
__global__ __launch_bounds__(256) void k_convert(
        const float* __restrict__ x, unsigned short* __restrict__ xb,
        const float* __restrict__ Wr, const float* __restrict__ Wl,
        s16x8* __restrict__ wprep, int* __restrict__ cnt,
        int n4, int nxb, int N)
{
    int b = blockIdx.x;
    if (b < nxb) {
        int t = b * 256 + threadIdx.x;
        if (t >= n4) return;
        float4 v = ((const float4*)x)[t];
        ushort4 o;
        o.x = (unsigned short)f2bf(v.x);
        o.y = (unsigned short)f2bf(v.y);
        o.z = (unsigned short)f2bf(v.z);
        o.w = (unsigned short)f2bf(v.w);
        ((ushort4*)xb)[t] = o;
    } else if (b < nxb + 16) {
        if (!wprep) return;
        int s = (b - nxb) * 256 + threadIdx.x;
        if (s >= 4096) return;
        int f = s >> 6, il = s & 63;
        int nt = f >> 3, ks = f & 7;
        int col = nt * 16 + (il & 15);
        int k   = ks * 32 + (il >> 4) * 8;
        const float* Wsrc = (k < 128) ? Wr : Wl;
        int k0 = k & 127;
        const float4* wp = (const float4*)(Wsrc + (size_t)col * 128 + k0);
        float4 w0 = wp[0], w1 = wp[1];
        s16x8 v;
        v[0] = (short)f2bf(w0.x); v[1] = (short)f2bf(w0.y);
        v[2] = (short)f2bf(w0.z); v[3] = (short)f2bf(w0.w);
        v[4] = (short)f2bf(w1.x); v[5] = (short)f2bf(w1.y);
        v[6] = (short)f2bf(w1.z); v[7] = (short)f2bf(w1.w);
        wprep[s] = v;
    } else {
        int z = (b - nxb - 16) * 256 + threadIdx.x;  // int4 index
        int base = z * 4;
        if (base + 4 <= N) {
            ((int4*)cnt)[z] = make_int4(0, 0, 0, 0);
        } else if (base < N) {
            for (int i = base; i < N; ++i) cnt[i] = 0;
        }
    }
}

// ---------- gather: one wave per dst node; bf16 mean of neighbor rows ----------
// reads xb rows (256B, one uint = 2 bf16 per lane), 4 edges in flight
__global__ __launch_bounds__(256) void k_gather_bf16(
        const unsigned int* __restrict__ xu, const int* __restrict__ srcS,
        const int* __restrict__ off, unsigned int* __restrict__ ab, int N)
{
    int d    = blockIdx.x * 4 + (threadIdx.x >> 6);
    int lane = threadIdx.x & 63;
    if (d >= N) return;
    int n1 = off[d];
    int n0 = (d > 0) ? off[d - 1] : 0;
    float ax0 = 0.f, ay0 = 0.f, ax1 = 0.f, ay1 = 0.f;
    float ax2 = 0.f, ay2 = 0.f, ax3 = 0.f, ay3 = 0.f;
    int p = n0;
    for (; p + 4 <= n1; p += 4) {
        int s0 = srcS[p],     s1 = srcS[p + 1];
        int s2 = srcS[p + 2], s3 = srcS[p + 3];
        unsigned int v0 = xu[(size_t)s0 * 64 + lane];
        unsigned int v1 = xu[(size_t)s1 * 64 + lane];
        unsigned int v2 = xu[(size_t)s2 * 64 + lane];
        unsigned int v3 = xu[(size_t)s3 * 64 + lane];
        ax0 += bflo2f(v0); ay0 += bfhi2f(v0);
        ax1 += bflo2f(v1); ay1 += bfhi2f(v1);
        ax2 += bflo2f(v2); ay2 += bfhi2f(v2);
        ax3 += bflo2f(v3); ay3 += bfhi2f(v3);
    }
    for (; p < n1; ++p) {
        int s = srcS[p];
        unsigned int v = xu[(size_t)s * 64 + lane];
        ax0 += bflo2f(v); ay0 += bfhi2f(v);
    }
    int n = n1 - n0;
    float inv = 1.0f / (float)max(n, 1);
    unsigned int pk = f2bf((ax0 + ax1 + ax2 + ax3) * inv)
                    | (f2bf((ay0 + ay1 + ay2 + ay3) * inv) << 16);
    ab[(size_t)d * 64 + lane] = pk;
}

// ---------- MFMA combine: out = [xb|ab] @ [Wr|Wl]^T + bl ----------
// B fragments in LDS (64 KiB), copied from wprep (or computed if wprep==null).
// Per wave: 16 rows x 128 cols; A-frag row = lane&15, k-slice = (lane>>4)*8.
// D layout (m89): row = (lane>>4)*4 + i, col = lane&15.
__global__ __launch_bounds__(256) void k_combine_mfma(
        const unsigned short* __restrict__ xb, const unsigned short* __restrict__ ab,
        const s16x8* __restrict__ wprep,
        const float* __restrict__ Wr, const float* __restrict__ Wl,
        const float* __restrict__ bl,
        float* __restrict__ out, int N, int T)
{
    __shared__ s16x8 Bf[64][64];                  // 65536 B
    int t = threadIdx.x;
    if (wprep) {
        const uint4* ws = (const uint4*)wprep;
        uint4* bd = (uint4*)&Bf[0][0];
        for (int s = t; s < 4096; s += 256) bd[s] = ws[s];
    } else {
        for (int s = t; s < 4096; s += 256) {
            int f = s >> 6, il = s & 63;
            int nt = f >> 3, ks = f & 7;
            int col = nt * 16 + (il & 15);
            int k   = ks * 32 + (il >> 4) * 8;
            const float* Wsrc = (k < 128) ? Wr : Wl;
            int k0 = k & 127;
            const float4* wp = (const float4*)(Wsrc + (size_t)col * 128 + k0);
            float4 w0 = wp[0], w1 = wp[1];
            s16x8 v;
            v[0] = (short)f2bf(w0.x); v[1] = (short)f2bf(w0.y);
            v[2] = (short)f2bf(w0.z); v[3] = (short)f2bf(w0.w);
            v[4] = (short)f2bf(w1.x); v[5] = (short)f2bf(w1.y);
            v[6] = (short)f2bf(w1.z); v[7] = (short)f2bf(w1.w);
            Bf[f][il] = v;
        }
    }
    __syncthreads();

    int wid = t >> 6, l = t & 63;
    int lr = l & 15, lg = l >> 4;
    float bias[8];
    #pragma unroll
    for (int nt = 0; nt < 8; ++nt) bias[nt] = bl[nt * 16 + lr];

    for (int tile = blockIdx.x; tile < T; tile += gridDim.x) {
        int rowbase = tile * 64 + wid * 16;
        int arow = min(rowbase + lr, N - 1);      // clamp for tail tile
        const s16x8* xr = (const s16x8*)(xb + (size_t)arow * 128);
        const s16x8* ar = (const s16x8*)(ab + (size_t)arow * 128);
        s16x8 af[8];
        #pragma unroll
        for (int ks = 0; ks < 4; ++ks) af[ks]     = xr[ks * 4 + lg];
        #pragma unroll
        for (int ks = 0; ks < 4; ++ks) af[4 + ks] = ar[ks * 4 + lg];

        f32x4 acc[8];
        #pragma unroll
        for (int nt = 0; nt < 8; ++nt) {
            float b = bias[nt];
            acc[nt] = (f32x4){b, b, b, b};
        }

        #pragma unroll
        for (int ks = 0; ks < 8; ++ks)
            #pragma unroll
            for (int nt = 0; nt < 8; ++nt)
                acc[nt] = __builtin_amdgcn_mfma_f32_16x16x32_bf16(
                              af[ks], Bf[nt * 8 + ks][l], acc[nt], 0, 0, 0);

        #pragma unroll
        for (int i = 0; i < 4; ++i) {
            int row = rowbase + lg * 4 + i;
            if (row < N) {
                float* op = out + (size_t)row * 128 + lr;
                #pragma unroll
                for (int nt = 0; nt < 8; ++nt) op[nt * 16] = acc[nt][i];
            }
        }
    }
}

// ======================= fallback path (small ws) =======================

__global__ __launch_bounds__(256) void k_gather_f32(
        const float* __restrict__ x, const int* __restrict__ srcS,
        const int* __restrict__ off, float* a, int N)
{
    int d    = blockIdx.x * 4 + (threadIdx.x >> 6);
    int lane = threadIdx.x & 63;
    if (d >= N) return;
    int n1 = off[d];
    int n0 = (d > 0) ? off[d - 1] : 0;
    const float2* x2 = (const float2*)x;
    float ax = 0.f, ay = 0.f;
    for (int p = n0; p < n1; ++p) {
        int s = srcS[p];
        float2 v = x2[(size_t)s * 64 + lane];
        ax += v.x; ay += v.y;
    }
    float inv = 1.0f / (float)max(n1 - n0, 1);
    float2 r; r.x = ax * inv; r.y = ay * inv;
    ((float2*)a)[(size_t)d * 64 + lane] = r;
}

__global__ __launch_bounds__(256) void k_zero(int* __restrict__ p, int n)
{
    int t = blockIdx.x * 256 + threadIdx.x;
    if (t < n) p[t] = 0;
}

__global__ __launch_bounds__(256) void k_combine_valu(
        const float* __restrict__ x, const float* a,
        const float* __restrict__ Wr, const float* __restrict__ Wl,
        const float* __restrict__ bl,
        float* out, int N)
{
    __shared__ uint4 WT4[64][64];
    for (int idx = threadIdx.x; idx < 64 * 64; idx += 256) {
        int g = idx >> 6, l = idx & 63;
        uint4 wv;
        unsigned int* wp = &wv.x;
        #pragma unroll
        for (int kk = 0; kk < 4; ++kk) {
            int k = g * 4 + kk;
            const float* Wsrc = (k < 128) ? Wr : Wl;
            int km = k & 127;
            unsigned int lo = f2bf(Wsrc[(size_t)l * 128 + km]);
            unsigned int hi = f2bf(Wsrc[(size_t)(l + 64) * 128 + km]);
            wp[kk] = lo | (hi << 16);
        }
        WT4[g][l] = wv;
    }
    __syncthreads();

    int wid = threadIdx.x >> 6, lane = threadIdx.x & 63;
    float b0 = bl[lane], b1 = bl[lane + 64];
    for (int row = blockIdx.x * 4 + wid; row < N; row += gridDim.x * 4) {
        const float4* xr = (const float4*)(x + (size_t)row * 128);
        const float4* ar = (const float4*)(a + (size_t)row * 128);
        float acc0 = b0, acc1 = b1;
        #pragma unroll 8
        for (int c = 0; c < 32; ++c) {
            uint4 w4 = WT4[c][lane];
            float4 q = xr[c];
            #pragma unroll
            for (int j = 0; j < 4; ++j) {
                unsigned int w = (&w4.x)[j];
                float f = (&q.x)[j];
                acc0 = fmaf(f, bflo2f(w), acc0);
                acc1 = fmaf(f, bfhi2f(w), acc1);
            }
        }
        #pragma unroll 8
        for (int c = 0; c < 32; ++c) {
            uint4 w4 = WT4[c + 32][lane];
            float4 q = ar[c];
            #pragma unroll
            for (int j = 0; j < 4; ++j) {
                unsigned int w = (&w4.x)[j];
                float f = (&q.x)[j];
                acc0 = fmaf(f, bflo2f(w), acc0);
                acc1 = fmaf(f, bfhi2f(w), acc1);
            }
        }
        out[(size_t)row * 128 + lane]      = acc0;
        out[(size_t)row * 128 + lane + 64] = acc1;
    }
}

__global__ __launch_bounds__(256) void k_scatter_legacy(
        const float* __restrict__ x,
        const int* __restrict__ src, const int* __restrict__ dst,
        float* __restrict__ agg, float* __restrict__ deg, int E)
{
    int e    = (int)((blockIdx.x * 256u + threadIdx.x) >> 6);
    int lane = threadIdx.x & 63;
    if (e >= E) return;
    int s = src[e];
    int d = dst[e];
    float2 v = ((const float2*)(x + (size_t)s * 128u))[lane];
    float* ar = agg + (size_t)d * 128u;
    unsafeAtomicAdd(ar + 2 * lane,     v.x);
    unsafeAtomicAdd(ar + 2 * lane + 1, v.y);
    if (lane == 0) unsafeAtomicAdd(deg + d, 1.0f);
}

__global__ __launch_bounds__(256) void k_finalize_legacy(
        float* agg, const float* __restrict__ deg, int N)
{
    int t = blockIdx.x * 256 + threadIdx.x;
    if (t >= N * 32) return;
    int node = t >> 5;
    float inv = 1.0f / fmaxf(deg[node], 1.0f);
    float4 v = ((const float4*)agg)[t];
    v.x *= inv; v.y *= inv; v.z *= inv; v.w *= inv;
    ((float4*)agg)[t] = v;
}

// ======================= launch =======================

extern "C" void kernel_launch(void* const* d_in, const int* in_sizes, int n_in,
                              void* d_out, int out_size, void* d_ws, size_t ws_size,
                              hipStream_t stream)
{
    const float* x  = (const float*)d_in[0];
    const int*   ei = (const int*)d_in[1];
    const float* Wl = (const float*)d_in[2];
    const float* bl = (const float*)d_in[3];
    const float* Wr = (const float*)d_in[4];
    float*      out = (float*)d_out;

    int N = in_sizes[0] / 128;
    int E = in_sizes[1] / 2;
    const int* src = ei;          // edge_index[0] = source nodes (j)
    const int* dst = ei + E;      // edge_index[1] = destination nodes (i)

    int nb = (N + 1023) / 1024;
    size_t aB  = (size_t)N * 128 * 4;              // f32 row block
    size_t bfB = (size_t)N * 128 * 2;              // bf16 row block

    // ws: cnt[N] off[N+1] bsum[nb] boff[nb] srcS[E] | xb | ab | wprep(64KB)
    size_t nInts = (size_t)N * 2 + 1 + 2 * (size_t)nb + (size_t)E;
    size_t intsB = ((nInts * 4) + 255) & ~(size_t)255;

    if (ws_size >= intsB + 2 * bfB && nb <= 1024) {
        // -------- MFMA path --------
        int* cnt  = (int*)d_ws;
        int* off  = cnt + N;
        int* bsum = off + N + 1;
        int* boff = bsum + nb;
        int* srcS = boff + nb;
        unsigned short* xb = (unsigned short*)((char*)d_ws + intsB);
        unsigned short* ab = xb + (size_t)N * 128;
        s16x8* wprep = (ws_size >= intsB + 2 * bfB + 65536)
                     ? (s16x8*)((char*)ab + bfB) : nullptr;

        int nxb = (N * 32 + 255) / 256;
        int nz4 = (N + 3) / 4;
        int nzb = (nz4 + 255) / 256;
        int ncv = nxb + 16 + nzb;                  // convert | wprep | zero-cnt

        k_convert <<<ncv, 256, 0, stream>>>(x, xb, Wr, Wl, wprep, cnt, N * 32, nxb, N);
        k_hist    <<<(E + 255) / 256, 256, 0, stream>>>(dst, cnt, E);
        k_scan1   <<<nb, 1024, 0, stream>>>(cnt, off, bsum, N);
        k_scan2   <<<1,  1024, 0, stream>>>(bsum, boff, off, nb, N, E);
        k_scan3   <<<nb, 1024, 0, stream>>>(off, boff, N);
        k_permute <<<(E + 255) / 256, 256, 0, stream>>>(src, dst, off, srcS, E);
        k_gather_bf16<<<(N + 3) / 4, 256, 0, stream>>>(
                (const unsigned int*)xb, srcS, off, (unsigned int*)ab, N);
        int T = (N + 63) / 64;
        k_combine_mfma<<<512, 256, 0, stream>>>(xb, ab, wprep, Wr, Wl, bl, out, N, T);
    } else if (ws_size >= intsB && nb <= 1024) {
        // -------- CSR + VALU path (a aliases out) --------
        int* cnt  = (int*)d_ws;
        int* off  = cnt + N;
        int* bsum = off + N + 1;
        int* boff = bsum + nb;
        int* srcS = boff + nb;
        float* a = (ws_size >= intsB + aB) ? (float*)((char*)d_ws + intsB) : out;

        k_zero    <<<(N + 255) / 256, 256, 0, stream>>>(cnt, N);
        k_hist    <<<(E + 255) / 256, 256, 0, stream>>>(dst, cnt, E);
        k_scan1   <<<nb, 1024, 0, stream>>>(cnt, off, bsum, N);
        k_scan2   <<<1,  1024, 0, stream>>>(bsum, boff, off, nb, N, E);
        k_scan3   <<<nb, 1024, 0, stream>>>(off, boff, N);
        k_permute <<<(E + 255) / 256, 256, 0, stream>>>(src, dst, off, srcS, E);
        k_gather_f32<<<(N + 3) / 4, 256, 0, stream>>>(x, srcS, off, a, N);
        k_combine_valu<<<1024, 256, 0, stream>>>(x, a, Wr, Wl, bl, out, N);
    } else {
        // -------- legacy atomic path --------
        float* agg = out;
        float* deg = (float*)d_ws;
        hipMemsetAsync(out, 0, aB, stream);
        hipMemsetAsync(deg, 0, (size_t)N * 4, stream);
        k_scatter_legacy <<<(E + 3) / 4, 256, 0, stream>>>(x, src, dst, agg, deg, E);
        k_finalize_legacy<<<(N * 32 + 255) / 256, 256, 0, stream>>>(agg, deg, N);
        k_combine_valu<<<1024, 256, 0, stream>>>(x, agg, Wr, Wl, bl, out, N);
    }
}